// Round 2
// baseline (105.413 us; speedup 1.0000x reference)
//
#include <hip/hip_runtime.h>
#include <hip/hip_bf16.h>
#include <stdint.h>

#define M_DIM 2048
#define N_DIM 4096
#define K_DIM 4096

#define BM 128
#define BN 256
#define BK 64

typedef __bf16 bf16x8 __attribute__((ext_vector_type(8)));
typedef float f32x4 __attribute__((ext_vector_type(4)));
typedef unsigned short ushort8_t __attribute__((ext_vector_type(8)));

__device__ __forceinline__ unsigned short f32_to_bf16_rne(float f) {
    union { float f; uint32_t u; } cvt;
    cvt.f = f;
    uint32_t u = cvt.u;
    uint32_t r = (u + 0x7fffu + ((u >> 16) & 1u)) >> 16;
    return (unsigned short)r;
}

__device__ __forceinline__ void gload_lds16(const void* g, void* l) {
    __builtin_amdgcn_global_load_lds(
        (__attribute__((address_space(1))) const void*)g,
        (__attribute__((address_space(3))) void*)l,
        16, 0, 0);
}

// ---------------------------------------------------------------------------
// x (f32 [M][K]) -> bf16 [M][K]
// ---------------------------------------------------------------------------
__global__ void convert_x_kernel(const float* __restrict__ x,
                                 unsigned short* __restrict__ xb, int n8) {
    int i = blockIdx.x * blockDim.x + threadIdx.x;
    int stride = gridDim.x * blockDim.x;
    for (; i < n8; i += stride) {
        const float4* p = (const float4*)(x + (size_t)i * 8);
        float4 v0 = p[0];
        float4 v1 = p[1];
        ushort8_t o;
        o[0] = f32_to_bf16_rne(v0.x);
        o[1] = f32_to_bf16_rne(v0.y);
        o[2] = f32_to_bf16_rne(v0.z);
        o[3] = f32_to_bf16_rne(v0.w);
        o[4] = f32_to_bf16_rne(v1.x);
        o[5] = f32_to_bf16_rne(v1.y);
        o[6] = f32_to_bf16_rne(v1.z);
        o[7] = f32_to_bf16_rne(v1.w);
        *(ushort8_t*)(xb + (size_t)i * 8) = o;
    }
}

// ---------------------------------------------------------------------------
// W (f32 [K][N]) -> Wt (bf16 [N][K])   tiled 64x64 transpose+convert
// ---------------------------------------------------------------------------
__global__ void transpose_convert_w(const float* __restrict__ W,
                                    unsigned short* __restrict__ Wt) {
    __shared__ float tile[64][65];
    const int k0 = blockIdx.y * 64;
    const int n0 = blockIdx.x * 64;
    const int t  = threadIdx.x;
    const int tx = t & 15;
    const int ty = t >> 4;

#pragma unroll
    for (int r = 0; r < 4; ++r) {
        int row = ty + 16 * r;
        float4 v = *(const float4*)(W + (size_t)(k0 + row) * N_DIM + n0 + tx * 4);
        tile[row][tx * 4 + 0] = v.x;
        tile[row][tx * 4 + 1] = v.y;
        tile[row][tx * 4 + 2] = v.z;
        tile[row][tx * 4 + 3] = v.w;
    }
    __syncthreads();
#pragma unroll
    for (int r = 0; r < 4; ++r) {
        int nrow = ty + 16 * r;
        ushort4 o;
        o.x = f32_to_bf16_rne(tile[tx * 4 + 0][nrow]);
        o.y = f32_to_bf16_rne(tile[tx * 4 + 1][nrow]);
        o.z = f32_to_bf16_rne(tile[tx * 4 + 2][nrow]);
        o.w = f32_to_bf16_rne(tile[tx * 4 + 3][nrow]);
        *(ushort4*)(Wt + (size_t)(n0 + nrow) * K_DIM + k0 + tx * 4) = o;
    }
}

// ---------------------------------------------------------------------------
// GEMM: C[m][n] = sum_k A[m][k] * Bt[n][k] + bias[n]
// Counted-vmcnt phase schedule (T1+T2+T3+T4+T5):
//   128x256 tile, BK=64 split into two 32-k subtiles, 8 waves (2Mx4N),
//   per-wave 64x64 output. LDS [buf][kk][rows][32k], dbuf = 96 KiB.
//   2 phases/K-tile, each: waitcnt vmcnt(6) lgkm(0); s_barrier; 8 ds_read;
//   stage 1 kk-unit (3 glds); setprio(1); 16 MFMA; setprio(0).
//   9 loads (3 units) always in flight — vmcnt never drains to 0.
// ---------------------------------------------------------------------------
__global__ __launch_bounds__(512, 2) void gemm_bf16(
    const unsigned short* __restrict__ A,
    const unsigned short* __restrict__ Bt,
    const float* __restrict__ bias,
    float* __restrict__ C) {
    // [buf][kk][row][32k] bf16; A rows=128 (8 KiB/subtile), B rows=256 (16 KiB)
    __shared__ unsigned short sA[2 * 2 * 128 * 32];  // 32 KiB
    __shared__ unsigned short sB[2 * 2 * 256 * 32];  // 64 KiB
    char* sAb = (char*)sA;
    char* sBb = (char*)sB;

    const int t    = threadIdx.x;
    const int lane = t & 63;
    const int wave = t >> 6;
    const int wm   = wave >> 2;  // 0..1
    const int wn   = wave & 3;   // 0..3
    const int lrow = lane & 15;
    const int lhi  = lane >> 4;
    // read-side swizzle: 16B chunk within a 64B subtile row
    const int phys16 = (lhi ^ (lrow & 3) ^ ((lrow >> 2) & 3)) * 16;

    // T1: XCD-aware swizzle, 256 WGs % 8 == 0 -> simple bijective form
    const int wg  = blockIdx.x;
    const int swz = (wg & 7) * 32 + (wg >> 3);
    const int m0  = (swz >> 4) * BM;
    const int n0  = (swz & 15) * BN;

    // stage one kk-subtile of tile `tile` into buffer `buf`
    auto stage = [&](int buf, int kk, int tile) {
        const size_t kbase = (size_t)tile * BK + kk * 32;
        {
            int c = t, row = c >> 2, p = c & 3;
            int l = p ^ (row & 3) ^ ((row >> 2) & 3);  // inverse-swizzled source
            gload_lds16(A + (size_t)(m0 + row) * K_DIM + kbase + l * 8,
                        sAb + (buf * 2 + kk) * 8192 + c * 16);
        }
        {
            int c = t, row = c >> 2, p = c & 3;
            int l = p ^ (row & 3) ^ ((row >> 2) & 3);
            gload_lds16(Bt + (size_t)(n0 + row) * K_DIM + kbase + l * 8,
                        sBb + (buf * 2 + kk) * 16384 + c * 16);
        }
        {
            int c = t + 512, row = c >> 2, p = c & 3;
            int l = p ^ (row & 3) ^ ((row >> 2) & 3);
            gload_lds16(Bt + (size_t)(n0 + row) * K_DIM + kbase + l * 8,
                        sBb + (buf * 2 + kk) * 16384 + c * 16);
        }
    };

    f32x4 acc[4][4];
#pragma unroll
    for (int i = 0; i < 4; ++i)
#pragma unroll
        for (int j = 0; j < 4; ++j) acc[i][j] = (f32x4)0.0f;

    const int NT = K_DIM / BK;  // 64

    // prologue: 3 units (9 loads) in flight
    stage(0, 0, 0);
    stage(0, 1, 0);
    stage(1, 0, 1);

#pragma unroll 2
    for (int tau = 0; tau < NT; ++tau) {
        const int cur = tau & 1;

        // ---------------- phase 0: consume kk=0 ----------------
        // drains this tile's kk0 unit (oldest); 2 units stay in flight
        asm volatile("s_waitcnt vmcnt(6) lgkmcnt(0)" ::: "memory");
        __builtin_amdgcn_s_barrier();
        __builtin_amdgcn_sched_barrier(0);
        {
            const int ab = (cur * 2 + 0) * 8192;
            const int bb = (cur * 2 + 0) * 16384;
            bf16x8 af[4], bf[4];
#pragma unroll
            for (int mi = 0; mi < 4; ++mi)
                af[mi] = *(const bf16x8*)(sAb + ab + (wm * 64 + mi * 16 + lrow) * 64 + phys16);
#pragma unroll
            for (int nj = 0; nj < 4; ++nj)
                bf[nj] = *(const bf16x8*)(sBb + bb + (wn * 64 + nj * 16 + lrow) * 64 + phys16);

            // stage (tau+1)'s kk1 into buf[(tau+1)&1] (last read at tau-1 P1)
            stage((tau + 1) & 1, 1, tau + 1 < NT ? tau + 1 : NT - 1);

            __builtin_amdgcn_s_setprio(1);
#pragma unroll
            for (int mi = 0; mi < 4; ++mi)
#pragma unroll
                for (int nj = 0; nj < 4; ++nj)
                    acc[mi][nj] = __builtin_amdgcn_mfma_f32_16x16x32_bf16(
                        af[mi], bf[nj], acc[mi][nj], 0, 0, 0);
            __builtin_amdgcn_s_setprio(0);
        }

        // ---------------- phase 1: consume kk=1 ----------------
        asm volatile("s_waitcnt vmcnt(6) lgkmcnt(0)" ::: "memory");
        __builtin_amdgcn_s_barrier();
        __builtin_amdgcn_sched_barrier(0);
        {
            const int ab = (cur * 2 + 1) * 8192;
            const int bb = (cur * 2 + 1) * 16384;
            bf16x8 af[4], bf[4];
#pragma unroll
            for (int mi = 0; mi < 4; ++mi)
                af[mi] = *(const bf16x8*)(sAb + ab + (wm * 64 + mi * 16 + lrow) * 64 + phys16);
#pragma unroll
            for (int nj = 0; nj < 4; ++nj)
                bf[nj] = *(const bf16x8*)(sBb + bb + (wn * 64 + nj * 16 + lrow) * 64 + phys16);

            // stage (tau+2)'s kk0 into buf[cur] (kk0 region read in P0 above)
            stage(cur, 0, tau + 2 < NT ? tau + 2 : NT - 1);

            __builtin_amdgcn_s_setprio(1);
#pragma unroll
            for (int mi = 0; mi < 4; ++mi)
#pragma unroll
                for (int nj = 0; nj < 4; ++nj)
                    acc[mi][nj] = __builtin_amdgcn_mfma_f32_16x16x32_bf16(
                        af[mi], bf[nj], acc[mi][nj], 0, 0, 0);
            __builtin_amdgcn_s_setprio(0);
        }
    }

    // epilogue: C/D layout col=lane&15, row=(lane>>4)*4+reg
#pragma unroll
    for (int nj = 0; nj < 4; ++nj) {
        int col  = n0 + wn * 64 + nj * 16 + lrow;
        float bv = bias[col];
#pragma unroll
        for (int mi = 0; mi < 4; ++mi) {
            int rbase = m0 + wm * 64 + mi * 16 + lhi * 4;
#pragma unroll
            for (int r = 0; r < 4; ++r) {
                C[(size_t)(rbase + r) * N_DIM + col] = acc[mi][nj][r] + bv;
            }
        }
    }
}

// ---------------------------------------------------------------------------
extern "C" void kernel_launch(void* const* d_in, const int* in_sizes, int n_in,
                              void* d_out, int out_size, void* d_ws, size_t ws_size,
                              hipStream_t stream) {
    const float* x    = (const float*)d_in[0];
    const float* w    = (const float*)d_in[1];
    const float* bias = (const float*)d_in[2];
    float* out        = (float*)d_out;

    unsigned short* xb = (unsigned short*)d_ws;
    unsigned short* wt = (unsigned short*)((char*)d_ws +
                          (size_t)M_DIM * K_DIM * sizeof(unsigned short));

    convert_x_kernel<<<2048, 256, 0, stream>>>(x, xb, M_DIM * K_DIM / 8);

    dim3 tgrid(N_DIM / 64, K_DIM / 64);
    transpose_convert_w<<<tgrid, 256, 0, stream>>>(w, wt);

    dim3 ggrid((M_DIM / BM) * (N_DIM / BN));
    gemm_bf16<<<ggrid, 512, 0, stream>>>(xb, wt, bias, out);
}

// Round 3
// 94.813 us; speedup vs baseline: 1.1118x; 1.1118x over previous
//
#include <hip/hip_runtime.h>
#include <hip/hip_bf16.h>
#include <stdint.h>

#define M_DIM 2048
#define N_DIM 4096
#define K_DIM 4096

#define BM 128
#define BN 256
#define BK 64

typedef __bf16 bf16x8 __attribute__((ext_vector_type(8)));
typedef float f32x4 __attribute__((ext_vector_type(4)));
typedef unsigned short ushort8_t __attribute__((ext_vector_type(8)));

__device__ __forceinline__ unsigned short f32_to_bf16_rne(float f) {
    union { float f; uint32_t u; } cvt;
    cvt.f = f;
    uint32_t u = cvt.u;
    uint32_t r = (u + 0x7fffu + ((u >> 16) & 1u)) >> 16;
    return (unsigned short)r;
}

__device__ __forceinline__ void gload_lds16(const void* g, void* l) {
    __builtin_amdgcn_global_load_lds(
        (__attribute__((address_space(1))) const void*)g,
        (__attribute__((address_space(3))) void*)l,
        16, 0, 0);
}

// ---------------------------------------------------------------------------
// x (f32 [M][K]) -> bf16 [M][K]
// ---------------------------------------------------------------------------
__global__ void convert_x_kernel(const float* __restrict__ x,
                                 unsigned short* __restrict__ xb, int n8) {
    int i = blockIdx.x * blockDim.x + threadIdx.x;
    int stride = gridDim.x * blockDim.x;
    for (; i < n8; i += stride) {
        const float4* p = (const float4*)(x + (size_t)i * 8);
        float4 v0 = p[0];
        float4 v1 = p[1];
        ushort8_t o;
        o[0] = f32_to_bf16_rne(v0.x);
        o[1] = f32_to_bf16_rne(v0.y);
        o[2] = f32_to_bf16_rne(v0.z);
        o[3] = f32_to_bf16_rne(v0.w);
        o[4] = f32_to_bf16_rne(v1.x);
        o[5] = f32_to_bf16_rne(v1.y);
        o[6] = f32_to_bf16_rne(v1.z);
        o[7] = f32_to_bf16_rne(v1.w);
        *(ushort8_t*)(xb + (size_t)i * 8) = o;
    }
}

// ---------------------------------------------------------------------------
// W (f32 [K][N]) -> Wt (bf16 [N][K])   tiled 64x64 transpose+convert
// ---------------------------------------------------------------------------
__global__ void transpose_convert_w(const float* __restrict__ W,
                                    unsigned short* __restrict__ Wt) {
    __shared__ float tile[64][65];
    const int k0 = blockIdx.y * 64;
    const int n0 = blockIdx.x * 64;
    const int t  = threadIdx.x;
    const int tx = t & 15;
    const int ty = t >> 4;

#pragma unroll
    for (int r = 0; r < 4; ++r) {
        int row = ty + 16 * r;
        float4 v = *(const float4*)(W + (size_t)(k0 + row) * N_DIM + n0 + tx * 4);
        tile[row][tx * 4 + 0] = v.x;
        tile[row][tx * 4 + 1] = v.y;
        tile[row][tx * 4 + 2] = v.z;
        tile[row][tx * 4 + 3] = v.w;
    }
    __syncthreads();
#pragma unroll
    for (int r = 0; r < 4; ++r) {
        int nrow = ty + 16 * r;
        ushort4 o;
        o.x = f32_to_bf16_rne(tile[tx * 4 + 0][nrow]);
        o.y = f32_to_bf16_rne(tile[tx * 4 + 1][nrow]);
        o.z = f32_to_bf16_rne(tile[tx * 4 + 2][nrow]);
        o.w = f32_to_bf16_rne(tile[tx * 4 + 3][nrow]);
        *(ushort4*)(Wt + (size_t)(n0 + nrow) * K_DIM + k0 + tx * 4) = o;
    }
}

// ---------------------------------------------------------------------------
// GEMM: C[m][n] = sum_k A[m][k] * Bt[n][k] + bias[n]
// Counted-vmcnt schedule + round-1 proven 0-conflict LDS geometry:
//   128x256 tile, BK=64 as 128B rows (8x16B slots, s = hi ^ (row&7)),
//   TRIPLE-buffered full tiles (144 KiB LDS, 1 WG/CU), 8 waves (2Mx4N).
//   Per K-tile: ONE waitcnt vmcnt(6) lgkm(0) + ONE barrier; 2 compute
//   phases (kk=0/1); stage tile tau+2 split 3+3 across the phases.
//   RAW: per-wave vmcnt(6) before barrier => all waves' tile-tau landed.
//   WAR: stage target buf (tau+2)%3 last read at tau-1, drained by the
//   lgkmcnt(0) preceding the same barrier.
// ---------------------------------------------------------------------------
__global__ __launch_bounds__(512, 2) void gemm_bf16(
    const unsigned short* __restrict__ A,
    const unsigned short* __restrict__ Bt,
    const float* __restrict__ bias,
    float* __restrict__ C) {
    __shared__ unsigned short sA[3][BM * BK];  // 3 x 16 KiB
    __shared__ unsigned short sB[3][BN * BK];  // 3 x 32 KiB

    const int t    = threadIdx.x;
    const int lane = t & 63;
    const int wave = t >> 6;
    const int wm   = wave >> 2;  // 0..1
    const int wn   = wave & 3;   // 0..3
    const int lrow = lane & 15;
    const int lhi  = lane >> 4;

    // T1: XCD-aware swizzle (256 WGs, %8==0 -> simple bijective form)
    const int wg  = blockIdx.x;
    const int swz = (wg & 7) * 32 + (wg >> 3);
    const int m0  = (swz >> 4) * BM;
    const int n0  = (swz & 15) * BN;

    // stage one 16B chunk: linear LDS dest + inverse-swizzled global source
    auto stageA = [&](int buf, int tile, int c) {
        int row = c >> 3, p = c & 7;
        int l   = p ^ (row & 7);
        gload_lds16(A + (size_t)(m0 + row) * K_DIM + tile * BK + l * 8,
                    (char*)sA[buf] + c * 16);
    };
    auto stageB = [&](int buf, int tile, int c) {
        int row = c >> 3, p = c & 7;
        int l   = p ^ (row & 7);
        gload_lds16(Bt + (size_t)(n0 + row) * K_DIM + tile * BK + l * 8,
                    (char*)sB[buf] + c * 16);
    };

    f32x4 acc[4][4];
#pragma unroll
    for (int i = 0; i < 4; ++i)
#pragma unroll
        for (int j = 0; j < 4; ++j) acc[i][j] = (f32x4)0.0f;

    const int NT = K_DIM / BK;  // 64

    // prologue: tiles 0 and 1 fully staged (12 loads in flight per thread)
    stageA(0, 0, t); stageA(0, 0, t + 512);
    stageB(0, 0, t); stageB(0, 0, t + 512);
    stageB(0, 0, t + 1024); stageB(0, 0, t + 1536);
    stageA(1, 1, t); stageA(1, 1, t + 512);
    stageB(1, 1, t); stageB(1, 1, t + 512);
    stageB(1, 1, t + 1024); stageB(1, 1, t + 1536);

    // per-thread fragment offsets (row&7 == lrow&7 since other terms are x8)
    const int rowOffA = (wm * 64 + lrow) * 128;  // bytes, + mi*16*128
    const int rowOffB = (wn * 64 + lrow) * 128;
    const int s0 = ((0 * 4 + lhi) ^ (lrow & 7)) * 16;  // kk=0 slot bytes
    const int s1 = ((1 * 4 + lhi) ^ (lrow & 7)) * 16;  // kk=1 slot bytes

    int bufC = 0, bufS = 2;
    for (int tau = 0; tau < NT; ++tau) {
        const int tile2 = (tau + 2 < NT) ? tau + 2 : NT - 1;

        // one wait + one barrier per K-tile; vmcnt NEVER drains to 0
        asm volatile("s_waitcnt vmcnt(6) lgkmcnt(0)" ::: "memory");
        __builtin_amdgcn_s_barrier();
        __builtin_amdgcn_sched_barrier(0);

        const char* bA = (const char*)sA[bufC];
        const char* bB = (const char*)sB[bufC];

        // ---- phase 0: kk=0 ----
        {
            bf16x8 af[4], bf[4];
#pragma unroll
            for (int mi = 0; mi < 4; ++mi)
                af[mi] = *(const bf16x8*)(bA + rowOffA + mi * 2048 + s0);
#pragma unroll
            for (int nj = 0; nj < 4; ++nj)
                bf[nj] = *(const bf16x8*)(bB + rowOffB + nj * 2048 + s0);

            stageA(bufS, tile2, t);
            stageA(bufS, tile2, t + 512);
            stageB(bufS, tile2, t);

            __builtin_amdgcn_s_setprio(1);
#pragma unroll
            for (int mi = 0; mi < 4; ++mi)
#pragma unroll
                for (int nj = 0; nj < 4; ++nj)
                    acc[mi][nj] = __builtin_amdgcn_mfma_f32_16x16x32_bf16(
                        af[mi], bf[nj], acc[mi][nj], 0, 0, 0);
            __builtin_amdgcn_s_setprio(0);
        }

        // ---- phase 1: kk=1 (same tile; no barrier needed) ----
        {
            bf16x8 af[4], bf[4];
#pragma unroll
            for (int mi = 0; mi < 4; ++mi)
                af[mi] = *(const bf16x8*)(bA + rowOffA + mi * 2048 + s1);
#pragma unroll
            for (int nj = 0; nj < 4; ++nj)
                bf[nj] = *(const bf16x8*)(bB + rowOffB + nj * 2048 + s1);

            stageB(bufS, tile2, t + 512);
            stageB(bufS, tile2, t + 1024);
            stageB(bufS, tile2, t + 1536);

            __builtin_amdgcn_s_setprio(1);
#pragma unroll
            for (int mi = 0; mi < 4; ++mi)
#pragma unroll
                for (int nj = 0; nj < 4; ++nj)
                    acc[mi][nj] = __builtin_amdgcn_mfma_f32_16x16x32_bf16(
                        af[mi], bf[nj], acc[mi][nj], 0, 0, 0);
            __builtin_amdgcn_s_setprio(0);
        }

        bufC = (bufC == 2) ? 0 : bufC + 1;
        bufS = (bufS == 2) ? 0 : bufS + 1;
    }

    // epilogue: C/D layout col=lane&15, row=(lane>>4)*4+reg
#pragma unroll
    for (int nj = 0; nj < 4; ++nj) {
        int col  = n0 + wn * 64 + nj * 16 + lrow;
        float bv = bias[col];
#pragma unroll
        for (int mi = 0; mi < 4; ++mi) {
            int rbase = m0 + wm * 64 + mi * 16 + lhi * 4;
#pragma unroll
            for (int r = 0; r < 4; ++r) {
                C[(size_t)(rbase + r) * N_DIM + col] = acc[mi][nj][r] + bv;
            }
        }
    }
}

// ---------------------------------------------------------------------------
extern "C" void kernel_launch(void* const* d_in, const int* in_sizes, int n_in,
                              void* d_out, int out_size, void* d_ws, size_t ws_size,
                              hipStream_t stream) {
    const float* x    = (const float*)d_in[0];
    const float* w    = (const float*)d_in[1];
    const float* bias = (const float*)d_in[2];
    float* out        = (float*)d_out;

    unsigned short* xb = (unsigned short*)d_ws;
    unsigned short* wt = (unsigned short*)((char*)d_ws +
                          (size_t)M_DIM * K_DIM * sizeof(unsigned short));

    convert_x_kernel<<<2048, 256, 0, stream>>>(x, xb, M_DIM * K_DIM / 8);

    dim3 tgrid(N_DIM / 64, K_DIM / 64);
    transpose_convert_w<<<tgrid, 256, 0, stream>>>(w, wt);

    dim3 ggrid((M_DIM / BM) * (N_DIM / BN));
    gemm_bf16<<<ggrid, 512, 0, stream>>>(xb, wt, bias, out);
}